// Round 6
// baseline (446.036 us; speedup 1.0000x reference)
//
#include <hip/hip_runtime.h>

typedef float v2f __attribute__((ext_vector_type(2)));
typedef _Float16 h2 __attribute__((ext_vector_type(2)));

__device__ __forceinline__ float frcp(float x){ return __builtin_amdgcn_rcpf(x); }
__device__ __forceinline__ float fexp2(float x){ return __builtin_amdgcn_exp2f(x); }
// sigmoid(x) = 1/(1+e^-x);  tanh(x) = 1 - 2/(e^{2x}+1)
__device__ __forceinline__ float tanh_(float x){ return 1.f - 2.f*frcp(1.f + fexp2(2.8853900817779268f*x)); }

#if __has_builtin(__builtin_amdgcn_fdot2)
#define FDOT2(a,b,c) __builtin_amdgcn_fdot2((a),(b),(c),false)
#else
#define FDOT2(a,b,c) ((c) + (float)(a).x*(float)(b).x + (float)(a).y*(float)(b).y)
#endif

// ---------------- embedding gather + concat -> x[b*128+t][128] fp32 ----------------
__global__ __launch_bounds__(256) void embed_kernel(
    const int* __restrict__ widx, const int* __restrict__ pidx,
    const float* __restrict__ wemb, const float* __restrict__ temb,
    float* __restrict__ x)
{
    int gid = blockIdx.x*256 + threadIdx.x;   // 262144 total
    int bt = gid >> 7, c = gid & 127;
    float v;
    if (c < 100) v = wemb[(size_t)widx[bt]*100 + c];
    else         v = temb[(size_t)pidx[bt]*28 + (c-100)];
    x[gid] = v;
}

// ---------------- pack w_hh (both dirs) to f16 pairs in thread-native layout --------------
// wpack[dir][t][j]: t = 4r+g owns pytorch gate-row g*128+r; j-th uint = (f16 w[2j], f16 w[2j+1]).
__global__ __launch_bounds__(256) void pack_kernel(
    const float* __restrict__ whh_f, const float* __restrict__ whh_b,
    unsigned* __restrict__ wpack)
{
    int id = blockIdx.x*256 + threadIdx.x;    // 65536 total
    int d = id >> 15, t = (id >> 6) & 511, j = id & 63;
    const float* whh = d ? whh_b : whh_f;
    int r = t >> 2, g = t & 3;
    const float* src = whh + (size_t)(g*128 + r)*128 + 2*j;
    unsigned short a = __builtin_bit_cast(unsigned short, (_Float16)src[0]);
    unsigned short b = __builtin_bit_cast(unsigned short, (_Float16)src[1]);
    wpack[((size_t)d*512 + t)*64 + j] = (unsigned)a | ((unsigned)b << 16);
}

// ---------------- generic C[m][n] = sum_k A[m][k]*B[n][k] (+biases) (opt exp(2x)) --------
// M fixed 2048 (grid.x=16, BM=128). grid.z selects B/bias/C set. BN=64, BK=16.
// permflag: output column p holds gate-row gr(p) = (p&3)*128 + (p>>2) (for LSTM layout).
// As columns swizzled g(m)=m+4*(m>>5) (round 7: 4-way -> 2-way bank spread).
__global__ __launch_bounds__(256) void gemm_kernel(
    const float* __restrict__ A, int K,
    const float* __restrict__ B0, const float* __restrict__ B1, int ldb,
    const float* __restrict__ bias0a, const float* __restrict__ bias0b,
    const float* __restrict__ bias1a, const float* __restrict__ bias1b,
    float* __restrict__ C0, float* __restrict__ C1, int ldc, int N,
    int expflag, int permflag)
{
    __shared__ float As[16][140];   // [k][g(m)], g(m)=m+4*(m>>5), max 139
    __shared__ float Bs[16][68];    // [k][n]
    const int z = blockIdx.z;
    const float* B  = z ? B1 : B0;
    const float* ba = z ? bias1a : bias0a;
    const float* bb = z ? bias1b : bias0b;
    float* C = z ? C1 : C0;
    const int m0 = blockIdx.x * 128;
    const int n0 = blockIdx.y * 64;
    const int tx = threadIdx.x;
    const int tm = tx & 15, tn = tx >> 4;       // 8x4 micro-tile
    const int arow = tx >> 1, akq = (tx & 1) * 8;
    const int brow = tx >> 2, bkq = (tx & 3) * 4;
    const int g_arow = arow + 4*(arow >> 5);
    const int rbase = tm*8 + 4*(tm >> 2);       // = g(tm*8)
    float acc[8][4];
    #pragma unroll
    for (int r=0;r<8;++r){
        #pragma unroll
        for (int c=0;c<4;++c) acc[r][c]=0.f; }
    const int bn = n0 + brow;
    const int brow_src = permflag ? ((bn & 3)*128 + (bn >> 2)) : bn;
    for (int k0 = 0; k0 < K; k0 += 16) {
        const float* ap = A + (size_t)(m0+arow)*K + k0 + akq;
        float4 a0 = *(const float4*)ap;
        float4 a1 = *(const float4*)(ap+4);
        float4 bv = make_float4(0.f,0.f,0.f,0.f);
        if (bn < N) {
            const float* bp = B + (size_t)brow_src*ldb + k0 + bkq;
            bv = *(const float4*)bp;
        }
        __syncthreads();
        As[akq+0][g_arow]=a0.x; As[akq+1][g_arow]=a0.y; As[akq+2][g_arow]=a0.z; As[akq+3][g_arow]=a0.w;
        As[akq+4][g_arow]=a1.x; As[akq+5][g_arow]=a1.y; As[akq+6][g_arow]=a1.z; As[akq+7][g_arow]=a1.w;
        Bs[bkq+0][brow]=bv.x; Bs[bkq+1][brow]=bv.y; Bs[bkq+2][brow]=bv.z; Bs[bkq+3][brow]=bv.w;
        __syncthreads();
        #pragma unroll
        for (int kk = 0; kk < 16; ++kk) {
            float4 av0 = *(const float4*)&As[kk][rbase];
            float4 av1 = *(const float4*)&As[kk][rbase+4];
            float4 bvv = *(const float4*)&Bs[kk][tn*4];
            float a[8] = {av0.x,av0.y,av0.z,av0.w,av1.x,av1.y,av1.z,av1.w};
            float b[4] = {bvv.x,bvv.y,bvv.z,bvv.w};
            #pragma unroll
            for (int r=0;r<8;++r){
                #pragma unroll
                for (int c=0;c<4;++c)
                    acc[r][c] = fmaf(a[r], b[c], acc[r][c]);
            }
        }
    }
    float bias[4];
    #pragma unroll
    for (int c=0;c<4;++c) {
        int n = n0 + tn*4 + c;
        int nsrc = permflag ? ((n & 3)*128 + (n >> 2)) : n;
        float v = 0.f;
        if (n < N) {
            if (ba) v += ba[nsrc];
            if (bb) v += bb[nsrc];
        }
        bias[c] = v;
    }
    #pragma unroll
    for (int r=0;r<8;++r) {
        int m = m0 + tm*8 + r;
        float v[4];
        #pragma unroll
        for (int c=0;c<4;++c) {
            float t = acc[r][c] + bias[c];
            if (expflag) t = fexp2(fminf(fmaxf(t,-40.f),40.f)*2.8853900817779268f); // e^{2t}
            v[c] = t;
        }
        int n = n0 + tn*4;
        if (n + 3 < N) {
            float4 st; st.x=v[0]; st.y=v[1]; st.z=v[2]; st.w=v[3];
            *(float4*)&C[(size_t)m*ldc + n] = st;
        } else {
            #pragma unroll
            for (int c=0;c<4;++c) if (n+c < N) C[(size_t)m*ldc + n + c] = v[c];
        }
    }
}

// ---------------- LSTM: one block per (b, dir); 1024 threads, 2-way K-split ---------------
// Thread tt owns gate-row gr=tt>>1 (gr=4r+g) and K-half kh=tt&1; 32 weight words held as
// EIGHT NAMED uint4s. Halves merged with shfl_xor(1); gates of row r combined by 4 shfls
// from the 8-lane group; c-state replicated in the 8 lanes. (Mapping correctness-proven:
// rounds 3/5 passed with it.)
// Round 14 (residency war, endgame): every attempt to keep LOOP-INVARIANT weight values
// in VGPRs failed — indexed array = scratch-demoted (R0/R1, VGPR=48); named values =
// remat'd/sunk into the loop (R3, VGPR=32); asm pin / volatile = miscompile (R2/R4);
// no-restrict = no effect (R5, VGPR=32). The compiler streams 128KB/block/step through
// L1 (~1918cy step = the whole kernel). Fix: make the weights LOOP-CARRIED instead of
// invariant. Each iteration does W ^= zz where zz is loaded from a workspace word that
// hipMemsetAsync zeroes on the stream: runtime-0, compile-time-opaque. Rematerializing
// W at step s would require replaying s xors — impossible; spilling would be a real
// per-iteration store+reload, which the spill model rejects. Plain C arithmetic, bit-exact
// (x^0=x), none of the R2/R4 exotic-form miscompile risk. Cost: 32 v_xor/thread/step,
// ~6x cheaper than the stream it removes.
__global__ __launch_bounds__(1024, 1)
void lstm_kernel(
    const float* __restrict__ xp,      // [dir][2048][512] permuted cols (col 4r+g <- gate row g*128+r)
    const unsigned* wpk,               // [2][512][64] f16 pairs
    const unsigned* zsrc,              // one word, memset to 0 on stream (opaque zero)
    float* hcat)                       // [16][128][256]
{
    const int b = blockIdx.x & 15;
    const int dir = blockIdx.x >> 4;
    const int tt = threadIdx.x;          // 0..1023
    const int gr = tt >> 1;              // gate-row 0..511 (gr = 4r+g)
    const int kh = tt & 1;               // K-half: h[kh*64 .. kh*64+63]
    const int gate = gr & 3, r = gr >> 2;
    const int lbase = (tt & 63) & ~7;    // 8-lane row group base within wave
    // activation constants: sig(x)=1/(1+2^(-x*log2e)); tanh(x)=1-2/(1+2^(2x*log2e))
    const float kexp = (gate == 2) ? 2.8853900817779268f : -1.4426950408889634f;
    const float mA   = (gate == 2) ? -2.f : 1.f;
    const float mB   = (gate == 2) ?  1.f : 0.f;

    // 8 named uint4 = 32 weight words = w for h[kh*64 .. kh*64+63] of gate-row gr.
    uint4 W0,W1,W2,W3,W4,W5,W6,W7;
    {
        const uint4* wr = (const uint4*)(wpk + (((size_t)dir*512 + gr)*64 + (kh << 5)));
        W0 = wr[0]; W1 = wr[1]; W2 = wr[2]; W3 = wr[3];
        W4 = wr[4]; W5 = wr[5]; W6 = wr[6]; W7 = wr[7];
    }
    const unsigned zz = zsrc[0];   // runtime 0, compile-time opaque (hoisted to one reg)

    __shared__ _Float16 h_lds[2][128];
    float c = 0.f;
    if (tt < 128) h_lds[0][tt] = (_Float16)0.f;
    __syncthreads();

    const float* xpd = xp + (size_t)dir*(2048*512) + (size_t)b*(128*512);
    float xpv = xpd[(dir ? 127 : 0)*512 + gr];
    for (int s = 0; s < 128; ++s) {
        // Loop-carried redefinition of the weight registers (zz == 0, bit-exact no-op):
        // blocks rematerialization/sinking of the weight loads into the loop.
        W0.x ^= zz; W0.y ^= zz; W0.z ^= zz; W0.w ^= zz;
        W1.x ^= zz; W1.y ^= zz; W1.z ^= zz; W1.w ^= zz;
        W2.x ^= zz; W2.y ^= zz; W2.z ^= zz; W2.w ^= zz;
        W3.x ^= zz; W3.y ^= zz; W3.z ^= zz; W3.w ^= zz;
        W4.x ^= zz; W4.y ^= zz; W4.z ^= zz; W4.w ^= zz;
        W5.x ^= zz; W5.y ^= zz; W5.z ^= zz; W5.w ^= zz;
        W6.x ^= zz; W6.y ^= zz; W6.z ^= zz; W6.w ^= zz;
        W7.x ^= zz; W7.y ^= zz; W7.z ^= zz; W7.w ^= zz;
        const int ts = dir ? (127 - s) : s;
        // branchless prefetch of next step's xp (clamped; last-iter load is harmless)
        const int tsn = dir ? (126 - s < 0 ? 0 : 126 - s) : (s + 1 > 127 ? 127 : s + 1);
        float xnext = xpd[tsn*512 + gr];
        // this thread's K-half of h: bytes kh*128 .. kh*128+127 (broadcast: 2 distinct
        // addresses per wave = free 2-way)
        const uint4* hb = (const uint4*)((const char*)&h_lds[s & 1][0] + (kh << 7));
        float A0=0.f, A1=0.f, A2=0.f, A3=0.f;
        #define DOT4(WV, J) { uint4 u = hb[J]; \
            A0 = FDOT2(__builtin_bit_cast(h2, WV.x), __builtin_bit_cast(h2, u.x), A0); \
            A1 = FDOT2(__builtin_bit_cast(h2, WV.y), __builtin_bit_cast(h2, u.y), A1); \
            A2 = FDOT2(__builtin_bit_cast(h2, WV.z), __builtin_bit_cast(h2, u.z), A2); \
            A3 = FDOT2(__builtin_bit_cast(h2, WV.w), __builtin_bit_cast(h2, u.w), A3); }
        DOT4(W0,0) DOT4(W1,1) DOT4(W2,2) DOT4(W3,3)
        DOT4(W4,4) DOT4(W5,5) DOT4(W6,6) DOT4(W7,7)
        #undef DOT4
        float half = (A0+A1)+(A2+A3);
        half += __shfl_xor(half, 1, 64);          // merge the two K-halves of row gr
        float dot = xpv + half;
        // activated gate value (sig for i,f,o; tanh for g) — redundant in both k-lanes
        float act = fmaf(mA, frcp(1.f + fexp2(kexp*dot)), mB);
        // 8-lane group broadcast: gates of row r sit at lanes lbase+2g (+kh duplicate)
        float i_ = __shfl(act, lbase+0, 64);
        float f_ = __shfl(act, lbase+2, 64);
        float g_ = __shfl(act, lbase+4, 64);
        float o_ = __shfl(act, lbase+6, 64);
        c = f_*c + i_*g_;                  // redundant in all 8 lanes, consistent
        float h = o_ * tanh_(c);
        if ((tt & 7) == 0) {
            h_lds[(s & 1) ^ 1][r] = (_Float16)h;
            hcat[((size_t)b*128 + ts)*256 + dir*128 + r] = h;
        }
        xpv = xnext;
        __syncthreads();
    }
}

// ------------- pairwise scorer: out[(i*128+j)*16+b] = S + sum_k w2_k / (ea_ik*eb_jk + 1) ----
// w2[k] = -2*fc2_w[k], S = sum(fc2_w)+fc2_b computed in-block (prep fused).
__global__ __launch_bounds__(256) void pair_kernel(
    const float* __restrict__ ea, const float* __restrict__ eb,
    const float* __restrict__ fc2w, const float* __restrict__ fc2b,
    float* __restrict__ out)
{
    __shared__ float eas[32][100];
    __shared__ float ebs[32][100];
    __shared__ float w2s[100];
    __shared__ float red[128];
    const int it = blockIdx.x * 32, jt = blockIdx.y * 32, b = blockIdx.z;
    const int tx = threadIdx.x;
    const float* eab = ea + (size_t)b*12800;
    const float* ebb = eb + (size_t)b*12800;
    for (int idx = tx; idx < 3200; idx += 256) {
        int r = idx / 100;
        int cc = idx - r*100;
        eas[r][cc] = eab[(it + r)*100 + cc];
        ebs[r][cc] = ebb[(jt + r)*100 + cc];
    }
    if (tx < 128) {
        float wv = (tx < 100) ? fc2w[tx] : 0.f;
        if (tx < 100) w2s[tx] = -2.f*wv;
        red[tx] = wv;
    }
    __syncthreads();
    for (int s2 = 64; s2 > 0; s2 >>= 1) {
        if (tx < s2) red[tx] += red[tx+s2];
        __syncthreads();
    }
    const float S = red[0] + fc2b[0];
    const int jp = tx & 15, ip = tx >> 4;
    const int i0 = ip*2, j0 = jp*2;
    float acc00=S, acc01=S, acc10=S, acc11=S;
    #pragma unroll
    for (int k = 0; k < 100; k += 4) {
        float4 A0 = *(const float4*)&eas[i0][k];
        float4 A1 = *(const float4*)&eas[i0+1][k];
        float4 B0 = *(const float4*)&ebs[j0][k];
        float4 B1 = *(const float4*)&ebs[j0+1][k];
        float4 W  = *(const float4*)&w2s[k];
        acc00 = fmaf(W.x, frcp(fmaf(A0.x,B0.x,1.f)), acc00);
        acc01 = fmaf(W.x, frcp(fmaf(A0.x,B1.x,1.f)), acc01);
        acc10 = fmaf(W.x, frcp(fmaf(A1.x,B0.x,1.f)), acc10);
        acc11 = fmaf(W.x, frcp(fmaf(A1.x,B1.x,1.f)), acc11);
        acc00 = fmaf(W.y, frcp(fmaf(A0.y,B0.y,1.f)), acc00);
        acc01 = fmaf(W.y, frcp(fmaf(A0.y,B1.y,1.f)), acc01);
        acc10 = fmaf(W.y, frcp(fmaf(A1.y,B0.y,1.f)), acc10);
        acc11 = fmaf(W.y, frcp(fmaf(A1.y,B1.y,1.f)), acc11);
        acc00 = fmaf(W.z, frcp(fmaf(A0.z,B0.z,1.f)), acc00);
        acc01 = fmaf(W.z, frcp(fmaf(A0.z,B1.z,1.f)), acc01);
        acc10 = fmaf(W.z, frcp(fmaf(A1.z,B0.z,1.f)), acc10);
        acc11 = fmaf(W.z, frcp(fmaf(A1.z,B1.z,1.f)), acc11);
        acc00 = fmaf(W.w, frcp(fmaf(A0.w,B0.w,1.f)), acc00);
        acc01 = fmaf(W.w, frcp(fmaf(A0.w,B1.w,1.f)), acc01);
        acc10 = fmaf(W.w, frcp(fmaf(A1.w,B0.w,1.f)), acc10);
        acc11 = fmaf(W.w, frcp(fmaf(A1.w,B1.w,1.f)), acc11);
    }
    const int gi0 = it + i0, gj0 = jt + j0;
    out[((size_t)(gi0  )*128 + gj0  )*16 + b] = acc00;
    out[((size_t)(gi0  )*128 + gj0+1)*16 + b] = acc01;
    out[((size_t)(gi0+1)*128 + gj0  )*16 + b] = acc10;
    out[((size_t)(gi0+1)*128 + gj0+1)*16 + b] = acc11;
}

extern "C" void kernel_launch(void* const* d_in, const int* in_sizes, int n_in,
                              void* d_out, int out_size, void* d_ws, size_t ws_size,
                              hipStream_t stream)
{
    (void)in_sizes; (void)n_in; (void)out_size; (void)ws_size;
    const int*   widx = (const int*)d_in[0];
    const int*   pidx = (const int*)d_in[1];
    const float* wemb = (const float*)d_in[4];
    const float* temb = (const float*)d_in[5];
    const float* w_ih_l0f = (const float*)d_in[6];
    const float* w_hh_l0f = (const float*)d_in[7];
    const float* b_ih_l0f = (const float*)d_in[8];
    const float* b_hh_l0f = (const float*)d_in[9];
    const float* w_ih_l0b = (const float*)d_in[10];
    const float* w_hh_l0b = (const float*)d_in[11];
    const float* b_ih_l0b = (const float*)d_in[12];
    const float* b_hh_l0b = (const float*)d_in[13];
    const float* w_ih_l1f = (const float*)d_in[14];
    const float* w_hh_l1f = (const float*)d_in[15];
    const float* b_ih_l1f = (const float*)d_in[16];
    const float* b_hh_l1f = (const float*)d_in[17];
    const float* w_ih_l1b = (const float*)d_in[18];
    const float* w_hh_l1b = (const float*)d_in[19];
    const float* b_ih_l1b = (const float*)d_in[20];
    const float* b_hh_l1b = (const float*)d_in[21];
    const float* fc1_w = (const float*)d_in[22];
    const float* fc1_b = (const float*)d_in[23];
    const float* fc2_w = (const float*)d_in[24];
    const float* fc2_b = (const float*)d_in[25];

    float* ws  = (float*)d_ws;
    float* x   = ws;                  // 262144
    float* xp0 = x + 262144;          // 2 * 1048576
    float* h1  = xp0 + 2097152;       // 524288
    float* xp1 = h1 + 524288;         // 2 * 1048576
    float* h2  = xp1 + 2097152;       // 524288
    float* ea  = h2 + 524288;         // 204800
    float* eb  = ea + 204800;         // 204800
    unsigned* wpk0 = (unsigned*)(eb + 204800);   // 65536 uints (layer0 f16 weights)
    unsigned* wpk1 = wpk0 + 65536;               // 65536 uints (layer1)
    unsigned* zbuf = wpk1 + 65536;               // 1 uint, opaque zero
    // total ~6.23M floats ~= 25 MB

    hipMemsetAsync(zbuf, 0, 4, stream);
    embed_kernel<<<1024, 256, 0, stream>>>(widx, pidx, wemb, temb, x);
    pack_kernel<<<256, 256, 0, stream>>>(w_hh_l0f, w_hh_l0b, wpk0);
    pack_kernel<<<256, 256, 0, stream>>>(w_hh_l1f, w_hh_l1b, wpk1);
    // layer 0 input projections (both dirs in grid.z), gate-permuted columns
    gemm_kernel<<<dim3(16,8,2), 256, 0, stream>>>(x, 128,
        w_ih_l0f, w_ih_l0b, 128,
        b_ih_l0f, b_hh_l0f, b_ih_l0b, b_hh_l0b,
        xp0, xp0 + 1048576, 512, 512, 0, 1);
    lstm_kernel<<<32, 1024, 0, stream>>>(xp0, wpk0, zbuf, h1);
    // layer 1 input projections, gate-permuted columns
    gemm_kernel<<<dim3(16,8,2), 256, 0, stream>>>(h1, 256,
        w_ih_l1f, w_ih_l1b, 256,
        b_ih_l1f, b_hh_l1f, b_ih_l1b, b_hh_l1b,
        xp1, xp1 + 1048576, 512, 512, 0, 1);
    lstm_kernel<<<32, 1024, 0, stream>>>(xp1, wpk1, zbuf, h2);
    // fc1: a = h2@wa^T -> ea = exp(2a); bp = h2@wb^T + fc1_b -> eb = exp(2bp)
    gemm_kernel<<<dim3(16,2,2), 256, 0, stream>>>(h2, 256,
        fc1_w, fc1_w + 256, 512,
        nullptr, nullptr, fc1_b, nullptr,
        ea, eb, 100, 100, 1, 0);
    pair_kernel<<<dim3(4,4,16), 256, 0, stream>>>(ea, eb, fc2_w, fc2_b, (float*)d_out);
}

// Round 7
// 422.224 us; speedup vs baseline: 1.0564x; 1.0564x over previous
//
#include <hip/hip_runtime.h>

typedef float v2f __attribute__((ext_vector_type(2)));
typedef _Float16 h2 __attribute__((ext_vector_type(2)));

__device__ __forceinline__ float frcp(float x){ return __builtin_amdgcn_rcpf(x); }
__device__ __forceinline__ float fexp2(float x){ return __builtin_amdgcn_exp2f(x); }
// sigmoid(x) = 1/(1+e^-x);  tanh(x) = 1 - 2/(e^{2x}+1)
__device__ __forceinline__ float tanh_(float x){ return 1.f - 2.f*frcp(1.f + fexp2(2.8853900817779268f*x)); }

#if __has_builtin(__builtin_amdgcn_fdot2)
#define FDOT2(a,b,c) __builtin_amdgcn_fdot2((a),(b),(c),false)
#else
#define FDOT2(a,b,c) ((c) + (float)(a).x*(float)(b).x + (float)(a).y*(float)(b).y)
#endif

// ---------------- embedding gather + concat -> x[b*128+t][128] fp32 ----------------
__global__ __launch_bounds__(256) void embed_kernel(
    const int* __restrict__ widx, const int* __restrict__ pidx,
    const float* __restrict__ wemb, const float* __restrict__ temb,
    float* __restrict__ x)
{
    int gid = blockIdx.x*256 + threadIdx.x;   // 262144 total
    int bt = gid >> 7, c = gid & 127;
    float v;
    if (c < 100) v = wemb[(size_t)widx[bt]*100 + c];
    else         v = temb[(size_t)pidx[bt]*28 + (c-100)];
    x[gid] = v;
}

// ---------------- pack w_hh (both dirs) to f16 pairs in thread-native layout --------------
// wpack[dir][t][j]: t = 4r+g owns pytorch gate-row g*128+r; j-th uint = (f16 w[2j], f16 w[2j+1]).
__global__ __launch_bounds__(256) void pack_kernel(
    const float* __restrict__ whh_f, const float* __restrict__ whh_b,
    unsigned* __restrict__ wpack)
{
    int id = blockIdx.x*256 + threadIdx.x;    // 65536 total
    int d = id >> 15, t = (id >> 6) & 511, j = id & 63;
    const float* whh = d ? whh_b : whh_f;
    int r = t >> 2, g = t & 3;
    const float* src = whh + (size_t)(g*128 + r)*128 + 2*j;
    unsigned short a = __builtin_bit_cast(unsigned short, (_Float16)src[0]);
    unsigned short b = __builtin_bit_cast(unsigned short, (_Float16)src[1]);
    wpack[((size_t)d*512 + t)*64 + j] = (unsigned)a | ((unsigned)b << 16);
}

// ---------------- generic C[m][n] = sum_k A[m][k]*B[n][k] (+biases) (opt exp(2x)) --------
// M fixed 2048 (grid.x=16, BM=128). grid.z selects B/bias/C set. BN=64, BK=16.
// permflag: output column p holds gate-row gr(p) = (p&3)*128 + (p>>2) (for LSTM layout).
// As columns swizzled g(m)=m+4*(m>>5) (round 7: 4-way -> 2-way bank spread).
__global__ __launch_bounds__(256) void gemm_kernel(
    const float* __restrict__ A, int K,
    const float* __restrict__ B0, const float* __restrict__ B1, int ldb,
    const float* __restrict__ bias0a, const float* __restrict__ bias0b,
    const float* __restrict__ bias1a, const float* __restrict__ bias1b,
    float* __restrict__ C0, float* __restrict__ C1, int ldc, int N,
    int expflag, int permflag)
{
    __shared__ float As[16][140];   // [k][g(m)], g(m)=m+4*(m>>5), max 139
    __shared__ float Bs[16][68];    // [k][n]
    const int z = blockIdx.z;
    const float* B  = z ? B1 : B0;
    const float* ba = z ? bias1a : bias0a;
    const float* bb = z ? bias1b : bias0b;
    float* C = z ? C1 : C0;
    const int m0 = blockIdx.x * 128;
    const int n0 = blockIdx.y * 64;
    const int tx = threadIdx.x;
    const int tm = tx & 15, tn = tx >> 4;       // 8x4 micro-tile
    const int arow = tx >> 1, akq = (tx & 1) * 8;
    const int brow = tx >> 2, bkq = (tx & 3) * 4;
    const int g_arow = arow + 4*(arow >> 5);
    const int rbase = tm*8 + 4*(tm >> 2);       // = g(tm*8)
    float acc[8][4];
    #pragma unroll
    for (int r=0;r<8;++r){
        #pragma unroll
        for (int c=0;c<4;++c) acc[r][c]=0.f; }
    const int bn = n0 + brow;
    const int brow_src = permflag ? ((bn & 3)*128 + (bn >> 2)) : bn;
    for (int k0 = 0; k0 < K; k0 += 16) {
        const float* ap = A + (size_t)(m0+arow)*K + k0 + akq;
        float4 a0 = *(const float4*)ap;
        float4 a1 = *(const float4*)(ap+4);
        float4 bv = make_float4(0.f,0.f,0.f,0.f);
        if (bn < N) {
            const float* bp = B + (size_t)brow_src*ldb + k0 + bkq;
            bv = *(const float4*)bp;
        }
        __syncthreads();
        As[akq+0][g_arow]=a0.x; As[akq+1][g_arow]=a0.y; As[akq+2][g_arow]=a0.z; As[akq+3][g_arow]=a0.w;
        As[akq+4][g_arow]=a1.x; As[akq+5][g_arow]=a1.y; As[akq+6][g_arow]=a1.z; As[akq+7][g_arow]=a1.w;
        Bs[bkq+0][brow]=bv.x; Bs[bkq+1][brow]=bv.y; Bs[bkq+2][brow]=bv.z; Bs[bkq+3][brow]=bv.w;
        __syncthreads();
        #pragma unroll
        for (int kk = 0; kk < 16; ++kk) {
            float4 av0 = *(const float4*)&As[kk][rbase];
            float4 av1 = *(const float4*)&As[kk][rbase+4];
            float4 bvv = *(const float4*)&Bs[kk][tn*4];
            float a[8] = {av0.x,av0.y,av0.z,av0.w,av1.x,av1.y,av1.z,av1.w};
            float b[4] = {bvv.x,bvv.y,bvv.z,bvv.w};
            #pragma unroll
            for (int r=0;r<8;++r){
                #pragma unroll
                for (int c=0;c<4;++c)
                    acc[r][c] = fmaf(a[r], b[c], acc[r][c]);
            }
        }
    }
    float bias[4];
    #pragma unroll
    for (int c=0;c<4;++c) {
        int n = n0 + tn*4 + c;
        int nsrc = permflag ? ((n & 3)*128 + (n >> 2)) : n;
        float v = 0.f;
        if (n < N) {
            if (ba) v += ba[nsrc];
            if (bb) v += bb[nsrc];
        }
        bias[c] = v;
    }
    #pragma unroll
    for (int r=0;r<8;++r) {
        int m = m0 + tm*8 + r;
        float v[4];
        #pragma unroll
        for (int c=0;c<4;++c) {
            float t = acc[r][c] + bias[c];
            if (expflag) t = fexp2(fminf(fmaxf(t,-40.f),40.f)*2.8853900817779268f); // e^{2t}
            v[c] = t;
        }
        int n = n0 + tn*4;
        if (n + 3 < N) {
            float4 st; st.x=v[0]; st.y=v[1]; st.z=v[2]; st.w=v[3];
            *(float4*)&C[(size_t)m*ldc + n] = st;
        } else {
            #pragma unroll
            for (int c=0;c<4;++c) if (n+c < N) C[(size_t)m*ldc + n + c] = v[c];
        }
    }
}

// ---------------- LSTM: one block per (b, dir); round-3 map + f16 dot2 core ---------------
// Thread t: gate g = t&3 (pytorch order i,f,g,o), row r = t>>2. h in LDS as f16;
// dot = 64 v_dot2_f32_f16 (f32 accum). Quad shfl gate combine; 1 barrier/step.
// Round 15 (residency war endgame -> AGPR stash): every C-level attempt to keep the 64
// loop-invariant weight words in VGPRs failed — indexed array = scratch-demoted (R0/R1,
// VGPR=48); named values = remat'd into the loop (R3, VGPR=32); volatile / empty-asm pin
// = miscompile (R2/R4); no-restrict = no effect (R5); loop-carried xor = algebraically
// hoisted, stream kept (R6). The compiler re-streams 128KB/block/step through L1
// (~1490cy/step = the whole kernel time; FETCH flat, HBM ~1% => L2-resident stream).
// Fix: stash the weights in AGPRs. v_accvgpr_write-defined values are asm-opaque (NOT
// rematerializable — unlike a load, recomputing is impossible) and the AGPR pool is
// otherwise unused here (no MFMA), so the allocator keeps all 64 resident. Per-step, 64
// asm VOLATILE v_accvgpr_read (volatile => LICM cannot hoist) feed the dot2s and die
// immediately — VGPR pressure stays ~50. This is the documented CDNA spill mechanism
// driven by hand; single-operand "=a"/"a" asm is the standard pattern (HK/CK use it),
// structurally unlike R2's 16-tied-operand pin and R4's volatile vector loads.
__global__ __launch_bounds__(512, 2)
void lstm_kernel(
    const float* __restrict__ xp,      // [dir][2048][512] permuted cols (col 4r+g <- gate row g*128+r)
    const unsigned* __restrict__ wpk,  // [2][512][64] f16 pairs
    float* hcat)                       // [16][128][256]
{
    const int b = blockIdx.x & 15;
    const int dir = blockIdx.x >> 4;
    const int t = threadIdx.x;
    const int gate = t & 3, r = t >> 2;
    const int lane = t & 63, qbase = lane & ~3;
    // activation constants: sig(x)=1/(1+2^(-x*log2e)); tanh(x)=1-2/(1+2^(2x*log2e))
    const float kexp = (gate == 2) ? 2.8853900817779268f : -1.4426950408889634f;
    const float mA   = (gate == 2) ? -2.f : 1.f;
    const float mB   = (gate == 2) ?  1.f : 0.f;

    // 64 weight words -> 64 AGPRs.
    unsigned a00,a01,a02,a03,a04,a05,a06,a07,a08,a09,a10,a11,a12,a13,a14,a15,
             a16,a17,a18,a19,a20,a21,a22,a23,a24,a25,a26,a27,a28,a29,a30,a31,
             a32,a33,a34,a35,a36,a37,a38,a39,a40,a41,a42,a43,a44,a45,a46,a47,
             a48,a49,a50,a51,a52,a53,a54,a55,a56,a57,a58,a59,a60,a61,a62,a63;
    {
        const uint4* wr = (const uint4*)(wpk + ((size_t)dir*512 + t)*64);
        #define STASH4(I, A, B, C, D) { uint4 u = wr[I]; \
            asm volatile("v_accvgpr_write_b32 %0, %1" : "=a"(A) : "v"(u.x)); \
            asm volatile("v_accvgpr_write_b32 %0, %1" : "=a"(B) : "v"(u.y)); \
            asm volatile("v_accvgpr_write_b32 %0, %1" : "=a"(C) : "v"(u.z)); \
            asm volatile("v_accvgpr_write_b32 %0, %1" : "=a"(D) : "v"(u.w)); }
        STASH4(0,  a00,a01,a02,a03)  STASH4(1,  a04,a05,a06,a07)
        STASH4(2,  a08,a09,a10,a11)  STASH4(3,  a12,a13,a14,a15)
        STASH4(4,  a16,a17,a18,a19)  STASH4(5,  a20,a21,a22,a23)
        STASH4(6,  a24,a25,a26,a27)  STASH4(7,  a28,a29,a30,a31)
        STASH4(8,  a32,a33,a34,a35)  STASH4(9,  a36,a37,a38,a39)
        STASH4(10, a40,a41,a42,a43)  STASH4(11, a44,a45,a46,a47)
        STASH4(12, a48,a49,a50,a51)  STASH4(13, a52,a53,a54,a55)
        STASH4(14, a56,a57,a58,a59)  STASH4(15, a60,a61,a62,a63)
        #undef STASH4
    }

    __shared__ _Float16 h_lds[2][128];
    float c = 0.f;
    if (t < 128) h_lds[0][t] = (_Float16)0.f;
    __syncthreads();

    const float* xpd = xp + (size_t)dir*(2048*512) + (size_t)b*(128*512);
    float xpv = xpd[(dir ? 127 : 0)*512 + t];
    for (int s = 0; s < 128; ++s) {
        const int ts = dir ? (127 - s) : s;
        // branchless prefetch of next step's xp (clamped; last-iter load is harmless)
        const int tsn = dir ? (126 - s < 0 ? 0 : 126 - s) : (s + 1 > 127 ? 127 : s + 1);
        float xnext = xpd[tsn*512 + t];
        const uint4* hb = (const uint4*)&h_lds[s & 1][0];   // 16 x b128 broadcast reads
        float S0=0.f, S1=0.f, S2=0.f, S3=0.f;
        // read-from-AGPR + dot2; volatile read => executed every iteration, result dies
        #define RDOT(S, A, HU) { unsigned wv_; \
            asm volatile("v_accvgpr_read_b32 %0, %1" : "=v"(wv_) : "a"(A)); \
            S = FDOT2(__builtin_bit_cast(h2, wv_), __builtin_bit_cast(h2, (HU)), S); }
        { uint4 u = hb[0];  RDOT(S0,a00,u.x) RDOT(S1,a01,u.y) RDOT(S2,a02,u.z) RDOT(S3,a03,u.w) }
        { uint4 u = hb[1];  RDOT(S0,a04,u.x) RDOT(S1,a05,u.y) RDOT(S2,a06,u.z) RDOT(S3,a07,u.w) }
        { uint4 u = hb[2];  RDOT(S0,a08,u.x) RDOT(S1,a09,u.y) RDOT(S2,a10,u.z) RDOT(S3,a11,u.w) }
        { uint4 u = hb[3];  RDOT(S0,a12,u.x) RDOT(S1,a13,u.y) RDOT(S2,a14,u.z) RDOT(S3,a15,u.w) }
        { uint4 u = hb[4];  RDOT(S0,a16,u.x) RDOT(S1,a17,u.y) RDOT(S2,a18,u.z) RDOT(S3,a19,u.w) }
        { uint4 u = hb[5];  RDOT(S0,a20,u.x) RDOT(S1,a21,u.y) RDOT(S2,a22,u.z) RDOT(S3,a23,u.w) }
        { uint4 u = hb[6];  RDOT(S0,a24,u.x) RDOT(S1,a25,u.y) RDOT(S2,a26,u.z) RDOT(S3,a27,u.w) }
        { uint4 u = hb[7];  RDOT(S0,a28,u.x) RDOT(S1,a29,u.y) RDOT(S2,a30,u.z) RDOT(S3,a31,u.w) }
        { uint4 u = hb[8];  RDOT(S0,a32,u.x) RDOT(S1,a33,u.y) RDOT(S2,a34,u.z) RDOT(S3,a35,u.w) }
        { uint4 u = hb[9];  RDOT(S0,a36,u.x) RDOT(S1,a37,u.y) RDOT(S2,a38,u.z) RDOT(S3,a39,u.w) }
        { uint4 u = hb[10]; RDOT(S0,a40,u.x) RDOT(S1,a41,u.y) RDOT(S2,a42,u.z) RDOT(S3,a43,u.w) }
        { uint4 u = hb[11]; RDOT(S0,a44,u.x) RDOT(S1,a45,u.y) RDOT(S2,a46,u.z) RDOT(S3,a47,u.w) }
        { uint4 u = hb[12]; RDOT(S0,a48,u.x) RDOT(S1,a49,u.y) RDOT(S2,a50,u.z) RDOT(S3,a51,u.w) }
        { uint4 u = hb[13]; RDOT(S0,a52,u.x) RDOT(S1,a53,u.y) RDOT(S2,a54,u.z) RDOT(S3,a55,u.w) }
        { uint4 u = hb[14]; RDOT(S0,a56,u.x) RDOT(S1,a57,u.y) RDOT(S2,a58,u.z) RDOT(S3,a59,u.w) }
        { uint4 u = hb[15]; RDOT(S0,a60,u.x) RDOT(S1,a61,u.y) RDOT(S2,a62,u.z) RDOT(S3,a63,u.w) }
        #undef RDOT
        float dot = xpv + ((S0+S1)+(S2+S3));
        // activated gate value (sig for i,f,o; tanh for g)
        float act = fmaf(mA, frcp(1.f + fexp2(kexp*dot)), mB);
        // quad broadcast: every lane of the quad gets all 4 activated gates of row r
        float i_ = __shfl(act, qbase+0, 64);
        float f_ = __shfl(act, qbase+1, 64);
        float g_ = __shfl(act, qbase+2, 64);
        float o_ = __shfl(act, qbase+3, 64);
        c = f_*c + i_*g_;                  // redundant in all 4 lanes, consistent
        float h = o_ * tanh_(c);
        if (gate == 0) {
            h_lds[(s & 1) ^ 1][r] = (_Float16)h;
            hcat[((size_t)b*128 + ts)*256 + dir*128 + r] = h;
        }
        xpv = xnext;
        __syncthreads();
    }
}

// ------------- pairwise scorer: out[(i*128+j)*16+b] = S + sum_k w2_k / (ea_ik*eb_jk + 1) ----
// w2[k] = -2*fc2_w[k], S = sum(fc2_w)+fc2_b computed in-block (prep fused).
__global__ __launch_bounds__(256) void pair_kernel(
    const float* __restrict__ ea, const float* __restrict__ eb,
    const float* __restrict__ fc2w, const float* __restrict__ fc2b,
    float* __restrict__ out)
{
    __shared__ float eas[32][100];
    __shared__ float ebs[32][100];
    __shared__ float w2s[100];
    __shared__ float red[128];
    const int it = blockIdx.x * 32, jt = blockIdx.y * 32, b = blockIdx.z;
    const int tx = threadIdx.x;
    const float* eab = ea + (size_t)b*12800;
    const float* ebb = eb + (size_t)b*12800;
    for (int idx = tx; idx < 3200; idx += 256) {
        int r = idx / 100;
        int cc = idx - r*100;
        eas[r][cc] = eab[(it + r)*100 + cc];
        ebs[r][cc] = ebb[(jt + r)*100 + cc];
    }
    if (tx < 128) {
        float wv = (tx < 100) ? fc2w[tx] : 0.f;
        if (tx < 100) w2s[tx] = -2.f*wv;
        red[tx] = wv;
    }
    __syncthreads();
    for (int s2 = 64; s2 > 0; s2 >>= 1) {
        if (tx < s2) red[tx] += red[tx+s2];
        __syncthreads();
    }
    const float S = red[0] + fc2b[0];
    const int jp = tx & 15, ip = tx >> 4;
    const int i0 = ip*2, j0 = jp*2;
    float acc00=S, acc01=S, acc10=S, acc11=S;
    #pragma unroll
    for (int k = 0; k < 100; k += 4) {
        float4 A0 = *(const float4*)&eas[i0][k];
        float4 A1 = *(const float4*)&eas[i0+1][k];
        float4 B0 = *(const float4*)&ebs[j0][k];
        float4 B1 = *(const float4*)&ebs[j0+1][k];
        float4 W  = *(const float4*)&w2s[k];
        acc00 = fmaf(W.x, frcp(fmaf(A0.x,B0.x,1.f)), acc00);
        acc01 = fmaf(W.x, frcp(fmaf(A0.x,B1.x,1.f)), acc01);
        acc10 = fmaf(W.x, frcp(fmaf(A1.x,B0.x,1.f)), acc10);
        acc11 = fmaf(W.x, frcp(fmaf(A1.x,B1.x,1.f)), acc11);
        acc00 = fmaf(W.y, frcp(fmaf(A0.y,B0.y,1.f)), acc00);
        acc01 = fmaf(W.y, frcp(fmaf(A0.y,B1.y,1.f)), acc01);
        acc10 = fmaf(W.y, frcp(fmaf(A1.y,B0.y,1.f)), acc10);
        acc11 = fmaf(W.y, frcp(fmaf(A1.y,B1.y,1.f)), acc11);
        acc00 = fmaf(W.z, frcp(fmaf(A0.z,B0.z,1.f)), acc00);
        acc01 = fmaf(W.z, frcp(fmaf(A0.z,B1.z,1.f)), acc01);
        acc10 = fmaf(W.z, frcp(fmaf(A1.z,B0.z,1.f)), acc10);
        acc11 = fmaf(W.z, frcp(fmaf(A1.z,B1.z,1.f)), acc11);
        acc00 = fmaf(W.w, frcp(fmaf(A0.w,B0.w,1.f)), acc00);
        acc01 = fmaf(W.w, frcp(fmaf(A0.w,B1.w,1.f)), acc01);
        acc10 = fmaf(W.w, frcp(fmaf(A1.w,B0.w,1.f)), acc10);
        acc11 = fmaf(W.w, frcp(fmaf(A1.w,B1.w,1.f)), acc11);
    }
    const int gi0 = it + i0, gj0 = jt + j0;
    out[((size_t)(gi0  )*128 + gj0  )*16 + b] = acc00;
    out[((size_t)(gi0  )*128 + gj0+1)*16 + b] = acc01;
    out[((size_t)(gi0+1)*128 + gj0  )*16 + b] = acc10;
    out[((size_t)(gi0+1)*128 + gj0+1)*16 + b] = acc11;
}

extern "C" void kernel_launch(void* const* d_in, const int* in_sizes, int n_in,
                              void* d_out, int out_size, void* d_ws, size_t ws_size,
                              hipStream_t stream)
{
    (void)in_sizes; (void)n_in; (void)out_size; (void)ws_size;
    const int*   widx = (const int*)d_in[0];
    const int*   pidx = (const int*)d_in[1];
    const float* wemb = (const float*)d_in[4];
    const float* temb = (const float*)d_in[5];
    const float* w_ih_l0f = (const float*)d_in[6];
    const float* w_hh_l0f = (const float*)d_in[7];
    const float* b_ih_l0f = (const float*)d_in[8];
    const float* b_hh_l0f = (const float*)d_in[9];
    const float* w_ih_l0b = (const float*)d_in[10];
    const float* w_hh_l0b = (const float*)d_in[11];
    const float* b_ih_l0b = (const float*)d_in[12];
    const float* b_hh_l0b = (const float*)d_in[13];
    const float* w_ih_l1f = (const float*)d_in[14];
    const float* w_hh_l1f = (const float*)d_in[15];
    const float* b_ih_l1f = (const float*)d_in[16];
    const float* b_hh_l1f = (const float*)d_in[17];
    const float* w_ih_l1b = (const float*)d_in[18];
    const float* w_hh_l1b = (const float*)d_in[19];
    const float* b_ih_l1b = (const float*)d_in[20];
    const float* b_hh_l1b = (const float*)d_in[21];
    const float* fc1_w = (const float*)d_in[22];
    const float* fc1_b = (const float*)d_in[23];
    const float* fc2_w = (const float*)d_in[24];
    const float* fc2_b = (const float*)d_in[25];

    float* ws  = (float*)d_ws;
    float* x   = ws;                  // 262144
    float* xp0 = x + 262144;          // 2 * 1048576
    float* h1  = xp0 + 2097152;       // 524288
    float* xp1 = h1 + 524288;         // 2 * 1048576
    float* h2  = xp1 + 2097152;       // 524288
    float* ea  = h2 + 524288;         // 204800
    float* eb  = ea + 204800;         // 204800
    unsigned* wpk0 = (unsigned*)(eb + 204800);   // 65536 uints (layer0 f16 weights)
    unsigned* wpk1 = wpk0 + 65536;               // 65536 uints (layer1)
    // total ~6.1M floats ~= 24.5 MB

    embed_kernel<<<1024, 256, 0, stream>>>(widx, pidx, wemb, temb, x);
    pack_kernel<<<256, 256, 0, stream>>>(w_hh_l0f, w_hh_l0b, wpk0);
    pack_kernel<<<256, 256, 0, stream>>>(w_hh_l1f, w_hh_l1b, wpk1);
    // layer 0 input projections (both dirs in grid.z), gate-permuted columns
    gemm_kernel<<<dim3(16,8,2), 256, 0, stream>>>(x, 128,
        w_ih_l0f, w_ih_l0b, 128,
        b_ih_l0f, b_hh_l0f, b_ih_l0b, b_hh_l0b,
        xp0, xp0 + 1048576, 512, 512, 0, 1);
    lstm_kernel<<<32, 512, 0, stream>>>(xp0, wpk0, h1);
    // layer 1 input projections, gate-permuted columns
    gemm_kernel<<<dim3(16,8,2), 256, 0, stream>>>(h1, 256,
        w_ih_l1f, w_ih_l1b, 256,
        b_ih_l1f, b_hh_l1f, b_ih_l1b, b_hh_l1b,
        xp1, xp1 + 1048576, 512, 512, 0, 1);
    lstm_kernel<<<32, 512, 0, stream>>>(xp1, wpk1, h2);
    // fc1: a = h2@wa^T -> ea = exp(2a); bp = h2@wb^T + fc1_b -> eb = exp(2bp)
    gemm_kernel<<<dim3(16,2,2), 256, 0, stream>>>(h2, 256,
        fc1_w, fc1_w + 256, 512,
        nullptr, nullptr, fc1_b, nullptr,
        ea, eb, 100, 100, 1, 0);
    pair_kernel<<<dim3(4,4,16), 256, 0, stream>>>(ea, eb, fc2_w, fc2_b, (float*)d_out);
}

// Round 8
// 364.966 us; speedup vs baseline: 1.2221x; 1.1569x over previous
//
#include <hip/hip_runtime.h>

typedef float v2f __attribute__((ext_vector_type(2)));
typedef _Float16 h2 __attribute__((ext_vector_type(2)));

__device__ __forceinline__ float frcp(float x){ return __builtin_amdgcn_rcpf(x); }
__device__ __forceinline__ float fexp2(float x){ return __builtin_amdgcn_exp2f(x); }
// sigmoid(x) = 1/(1+e^-x);  tanh(x) = 1 - 2/(e^{2x}+1)
__device__ __forceinline__ float tanh_(float x){ return 1.f - 2.f*frcp(1.f + fexp2(2.8853900817779268f*x)); }

#if __has_builtin(__builtin_amdgcn_fdot2)
#define FDOT2(a,b,c) __builtin_amdgcn_fdot2((a),(b),(c),false)
#else
#define FDOT2(a,b,c) ((c) + (float)(a).x*(float)(b).x + (float)(a).y*(float)(b).y)
#endif

// ---------------- embedding gather + concat -> x[b*128+t][128] fp32 ----------------
__global__ __launch_bounds__(256) void embed_kernel(
    const int* __restrict__ widx, const int* __restrict__ pidx,
    const float* __restrict__ wemb, const float* __restrict__ temb,
    float* __restrict__ x)
{
    int gid = blockIdx.x*256 + threadIdx.x;   // 262144 total
    int bt = gid >> 7, c = gid & 127;
    float v;
    if (c < 100) v = wemb[(size_t)widx[bt]*100 + c];
    else         v = temb[(size_t)pidx[bt]*28 + (c-100)];
    x[gid] = v;
}

// ---------------- pack w_hh (both dirs) to f16 pairs in thread-native layout --------------
// wpack[dir][t][j]: t = 4r+g owns pytorch gate-row g*128+r; j-th uint = (f16 w[2j], f16 w[2j+1]).
__global__ __launch_bounds__(256) void pack_kernel(
    const float* __restrict__ whh_f, const float* __restrict__ whh_b,
    unsigned* __restrict__ wpack)
{
    int id = blockIdx.x*256 + threadIdx.x;    // 65536 total
    int d = id >> 15, t = (id >> 6) & 511, j = id & 63;
    const float* whh = d ? whh_b : whh_f;
    int r = t >> 2, g = t & 3;
    const float* src = whh + (size_t)(g*128 + r)*128 + 2*j;
    unsigned short a = __builtin_bit_cast(unsigned short, (_Float16)src[0]);
    unsigned short b = __builtin_bit_cast(unsigned short, (_Float16)src[1]);
    wpack[((size_t)d*512 + t)*64 + j] = (unsigned)a | ((unsigned)b << 16);
}

// ---------------- generic C[m][n] = sum_k A[m][k]*B[n][k] (+biases) (opt exp(2x)) --------
// M fixed 2048 (grid.x=16, BM=128). grid.z selects B/bias/C set. BN=64, BK=16.
// permflag: output column p holds gate-row gr(p) = (p&3)*128 + (p>>2) (for LSTM layout).
// As columns swizzled g(m)=m+4*(m>>5) (round 7: 4-way -> 2-way bank spread).
__global__ __launch_bounds__(256) void gemm_kernel(
    const float* __restrict__ A, int K,
    const float* __restrict__ B0, const float* __restrict__ B1, int ldb,
    const float* __restrict__ bias0a, const float* __restrict__ bias0b,
    const float* __restrict__ bias1a, const float* __restrict__ bias1b,
    float* __restrict__ C0, float* __restrict__ C1, int ldc, int N,
    int expflag, int permflag)
{
    __shared__ float As[16][140];   // [k][g(m)], g(m)=m+4*(m>>5), max 139
    __shared__ float Bs[16][68];    // [k][n]
    const int z = blockIdx.z;
    const float* B  = z ? B1 : B0;
    const float* ba = z ? bias1a : bias0a;
    const float* bb = z ? bias1b : bias0b;
    float* C = z ? C1 : C0;
    const int m0 = blockIdx.x * 128;
    const int n0 = blockIdx.y * 64;
    const int tx = threadIdx.x;
    const int tm = tx & 15, tn = tx >> 4;       // 8x4 micro-tile
    const int arow = tx >> 1, akq = (tx & 1) * 8;
    const int brow = tx >> 2, bkq = (tx & 3) * 4;
    const int g_arow = arow + 4*(arow >> 5);
    const int rbase = tm*8 + 4*(tm >> 2);       // = g(tm*8)
    float acc[8][4];
    #pragma unroll
    for (int r=0;r<8;++r){
        #pragma unroll
        for (int c=0;c<4;++c) acc[r][c]=0.f; }
    const int bn = n0 + brow;
    const int brow_src = permflag ? ((bn & 3)*128 + (bn >> 2)) : bn;
    for (int k0 = 0; k0 < K; k0 += 16) {
        const float* ap = A + (size_t)(m0+arow)*K + k0 + akq;
        float4 a0 = *(const float4*)ap;
        float4 a1 = *(const float4*)(ap+4);
        float4 bv = make_float4(0.f,0.f,0.f,0.f);
        if (bn < N) {
            const float* bp = B + (size_t)brow_src*ldb + k0 + bkq;
            bv = *(const float4*)bp;
        }
        __syncthreads();
        As[akq+0][g_arow]=a0.x; As[akq+1][g_arow]=a0.y; As[akq+2][g_arow]=a0.z; As[akq+3][g_arow]=a0.w;
        As[akq+4][g_arow]=a1.x; As[akq+5][g_arow]=a1.y; As[akq+6][g_arow]=a1.z; As[akq+7][g_arow]=a1.w;
        Bs[bkq+0][brow]=bv.x; Bs[bkq+1][brow]=bv.y; Bs[bkq+2][brow]=bv.z; Bs[bkq+3][brow]=bv.w;
        __syncthreads();
        #pragma unroll
        for (int kk = 0; kk < 16; ++kk) {
            float4 av0 = *(const float4*)&As[kk][rbase];
            float4 av1 = *(const float4*)&As[kk][rbase+4];
            float4 bvv = *(const float4*)&Bs[kk][tn*4];
            float a[8] = {av0.x,av0.y,av0.z,av0.w,av1.x,av1.y,av1.z,av1.w};
            float b[4] = {bvv.x,bvv.y,bvv.z,bvv.w};
            #pragma unroll
            for (int r=0;r<8;++r){
                #pragma unroll
                for (int c=0;c<4;++c)
                    acc[r][c] = fmaf(a[r], b[c], acc[r][c]);
            }
        }
    }
    float bias[4];
    #pragma unroll
    for (int c=0;c<4;++c) {
        int n = n0 + tn*4 + c;
        int nsrc = permflag ? ((n & 3)*128 + (n >> 2)) : n;
        float v = 0.f;
        if (n < N) {
            if (ba) v += ba[nsrc];
            if (bb) v += bb[nsrc];
        }
        bias[c] = v;
    }
    #pragma unroll
    for (int r=0;r<8;++r) {
        int m = m0 + tm*8 + r;
        float v[4];
        #pragma unroll
        for (int c=0;c<4;++c) {
            float t = acc[r][c] + bias[c];
            if (expflag) t = fexp2(fminf(fmaxf(t,-40.f),40.f)*2.8853900817779268f); // e^{2t}
            v[c] = t;
        }
        int n = n0 + tn*4;
        if (n + 3 < N) {
            float4 st; st.x=v[0]; st.y=v[1]; st.z=v[2]; st.w=v[3];
            *(float4*)&C[(size_t)m*ldc + n] = st;
        } else {
            #pragma unroll
            for (int c=0;c<4;++c) if (n+c < N) C[(size_t)m*ldc + n + c] = v[c];
        }
    }
}

// ---------------- LSTM: one block per (b, dir); round-3 map + f16 dot2 core ---------------
// Thread t: gate g = t&3 (pytorch order i,f,g,o), row r = t>>2. h in LDS as f16;
// dot = 64 v_dot2_f32_f16 (f32 accum). Quad shfl gate combine; 1 barrier/step.
// Round 16 (residency war resolved — asm laundering): the full history:
//   R0/R1: indexed weight array -> SROA demotes to scratch, per-step reload stream
//          (VGPR=48, 128KB/block/step through L1 = 1490cy step = the whole kernel).
//   R3:    named values -> loop-invariant loads are trivially rematerializable; regalloc
//          sinks them into the loop at zero modeled cost (VGPR=32, same stream).
//   R2/R4: empty 16-tied-operand pin asm / volatile vector loads -> miscompile.
//   R5:    dropping __restrict__ -> no effect.  R6: loop-carried xor -> algebraically
//          hoisted, stream kept + xor cost.
//   R7:    AGPR stash w/ 64 IN-LOOP volatile v_accvgpr_read -> CORRECT (proves
//          single-operand asm is safe) but slow: read->dot dep-stall every 2 instrs,
//          +64 VALU/step (2090cy step).
// Conclusion: asm-DEFINED values are the mechanism (LLVM can never rematerialize asm —
// recomputing is impossible, unlike a load). So launder each weight word through a
// one-time v_mov_b32 asm in the PROLOGUE: the loads die at the asm, the 64 asm-defined
// VGPR values must be carried across the loop (spill needs pressure; ~110 live regs is
// far under the 256-reg cap of launch_bounds(512,2); MachineSink won't sink into loops).
// Loop body is now the ideal one: 16 LDS broadcast reads + 64 dot2 + act + 4 shfl.
__global__ __launch_bounds__(512, 2)
void lstm_kernel(
    const float* __restrict__ xp,      // [dir][2048][512] permuted cols (col 4r+g <- gate row g*128+r)
    const unsigned* __restrict__ wpk,  // [2][512][64] f16 pairs
    float* hcat)                       // [16][128][256]
{
    const int b = blockIdx.x & 15;
    const int dir = blockIdx.x >> 4;
    const int t = threadIdx.x;
    const int gate = t & 3, r = t >> 2;
    const int lane = t & 63, qbase = lane & ~3;
    // activation constants: sig(x)=1/(1+2^(-x*log2e)); tanh(x)=1-2/(1+2^(2x*log2e))
    const float kexp = (gate == 2) ? 2.8853900817779268f : -1.4426950408889634f;
    const float mA   = (gate == 2) ? -2.f : 1.f;
    const float mB   = (gate == 2) ?  1.f : 0.f;

    // 64 weight words laundered into asm-defined VGPRs (one-time, prologue).
    unsigned w00,w01,w02,w03,w04,w05,w06,w07,w08,w09,w10,w11,w12,w13,w14,w15,
             w16,w17,w18,w19,w20,w21,w22,w23,w24,w25,w26,w27,w28,w29,w30,w31,
             w32,w33,w34,w35,w36,w37,w38,w39,w40,w41,w42,w43,w44,w45,w46,w47,
             w48,w49,w50,w51,w52,w53,w54,w55,w56,w57,w58,w59,w60,w61,w62,w63;
    {
        const uint4* wr = (const uint4*)(wpk + ((size_t)dir*512 + t)*64);
        #define LAUNDER4(I, A, B, C, D) { uint4 u = wr[I]; \
            asm volatile("v_mov_b32 %0, %1" : "=v"(A) : "v"(u.x)); \
            asm volatile("v_mov_b32 %0, %1" : "=v"(B) : "v"(u.y)); \
            asm volatile("v_mov_b32 %0, %1" : "=v"(C) : "v"(u.z)); \
            asm volatile("v_mov_b32 %0, %1" : "=v"(D) : "v"(u.w)); }
        LAUNDER4(0,  w00,w01,w02,w03)  LAUNDER4(1,  w04,w05,w06,w07)
        LAUNDER4(2,  w08,w09,w10,w11)  LAUNDER4(3,  w12,w13,w14,w15)
        LAUNDER4(4,  w16,w17,w18,w19)  LAUNDER4(5,  w20,w21,w22,w23)
        LAUNDER4(6,  w24,w25,w26,w27)  LAUNDER4(7,  w28,w29,w30,w31)
        LAUNDER4(8,  w32,w33,w34,w35)  LAUNDER4(9,  w36,w37,w38,w39)
        LAUNDER4(10, w40,w41,w42,w43)  LAUNDER4(11, w44,w45,w46,w47)
        LAUNDER4(12, w48,w49,w50,w51)  LAUNDER4(13, w52,w53,w54,w55)
        LAUNDER4(14, w56,w57,w58,w59)  LAUNDER4(15, w60,w61,w62,w63)
        #undef LAUNDER4
    }

    __shared__ _Float16 h_lds[2][128];
    float c = 0.f;
    if (t < 128) h_lds[0][t] = (_Float16)0.f;
    __syncthreads();

    const float* xpd = xp + (size_t)dir*(2048*512) + (size_t)b*(128*512);
    float xpv = xpd[(dir ? 127 : 0)*512 + t];
    for (int s = 0; s < 128; ++s) {
        const int ts = dir ? (127 - s) : s;
        // branchless prefetch of next step's xp (clamped; last-iter load is harmless)
        const int tsn = dir ? (126 - s < 0 ? 0 : 126 - s) : (s + 1 > 127 ? 127 : s + 1);
        float xnext = xpd[tsn*512 + t];
        const uint4* hb = (const uint4*)&h_lds[s & 1][0];   // 16 x b128 broadcast reads
        float S0=0.f, S1=0.f, S2=0.f, S3=0.f;
        #define DOT4(J, A, B, C, D) { uint4 u = hb[J]; \
            S0 = FDOT2(__builtin_bit_cast(h2, A), __builtin_bit_cast(h2, u.x), S0); \
            S1 = FDOT2(__builtin_bit_cast(h2, B), __builtin_bit_cast(h2, u.y), S1); \
            S2 = FDOT2(__builtin_bit_cast(h2, C), __builtin_bit_cast(h2, u.z), S2); \
            S3 = FDOT2(__builtin_bit_cast(h2, D), __builtin_bit_cast(h2, u.w), S3); }
        DOT4(0,  w00,w01,w02,w03)  DOT4(1,  w04,w05,w06,w07)
        DOT4(2,  w08,w09,w10,w11)  DOT4(3,  w12,w13,w14,w15)
        DOT4(4,  w16,w17,w18,w19)  DOT4(5,  w20,w21,w22,w23)
        DOT4(6,  w24,w25,w26,w27)  DOT4(7,  w28,w29,w30,w31)
        DOT4(8,  w32,w33,w34,w35)  DOT4(9,  w36,w37,w38,w39)
        DOT4(10, w40,w41,w42,w43)  DOT4(11, w44,w45,w46,w47)
        DOT4(12, w48,w49,w50,w51)  DOT4(13, w52,w53,w54,w55)
        DOT4(14, w56,w57,w58,w59)  DOT4(15, w60,w61,w62,w63)
        #undef DOT4
        float dot = xpv + ((S0+S1)+(S2+S3));
        // activated gate value (sig for i,f,o; tanh for g)
        float act = fmaf(mA, frcp(1.f + fexp2(kexp*dot)), mB);
        // quad broadcast: every lane of the quad gets all 4 activated gates of row r
        float i_ = __shfl(act, qbase+0, 64);
        float f_ = __shfl(act, qbase+1, 64);
        float g_ = __shfl(act, qbase+2, 64);
        float o_ = __shfl(act, qbase+3, 64);
        c = f_*c + i_*g_;                  // redundant in all 4 lanes, consistent
        float h = o_ * tanh_(c);
        if (gate == 0) {
            h_lds[(s & 1) ^ 1][r] = (_Float16)h;
            hcat[((size_t)b*128 + ts)*256 + dir*128 + r] = h;
        }
        xpv = xnext;
        __syncthreads();
    }
}

// ------------- pairwise scorer: out[(i*128+j)*16+b] = S + sum_k w2_k / (ea_ik*eb_jk + 1) ----
// w2[k] = -2*fc2_w[k], S = sum(fc2_w)+fc2_b computed in-block (prep fused).
__global__ __launch_bounds__(256) void pair_kernel(
    const float* __restrict__ ea, const float* __restrict__ eb,
    const float* __restrict__ fc2w, const float* __restrict__ fc2b,
    float* __restrict__ out)
{
    __shared__ float eas[32][100];
    __shared__ float ebs[32][100];
    __shared__ float w2s[100];
    __shared__ float red[128];
    const int it = blockIdx.x * 32, jt = blockIdx.y * 32, b = blockIdx.z;
    const int tx = threadIdx.x;
    const float* eab = ea + (size_t)b*12800;
    const float* ebb = eb + (size_t)b*12800;
    for (int idx = tx; idx < 3200; idx += 256) {
        int r = idx / 100;
        int cc = idx - r*100;
        eas[r][cc] = eab[(it + r)*100 + cc];
        ebs[r][cc] = ebb[(jt + r)*100 + cc];
    }
    if (tx < 128) {
        float wv = (tx < 100) ? fc2w[tx] : 0.f;
        if (tx < 100) w2s[tx] = -2.f*wv;
        red[tx] = wv;
    }
    __syncthreads();
    for (int s2 = 64; s2 > 0; s2 >>= 1) {
        if (tx < s2) red[tx] += red[tx+s2];
        __syncthreads();
    }
    const float S = red[0] + fc2b[0];
    const int jp = tx & 15, ip = tx >> 4;
    const int i0 = ip*2, j0 = jp*2;
    float acc00=S, acc01=S, acc10=S, acc11=S;
    #pragma unroll
    for (int k = 0; k < 100; k += 4) {
        float4 A0 = *(const float4*)&eas[i0][k];
        float4 A1 = *(const float4*)&eas[i0+1][k];
        float4 B0 = *(const float4*)&ebs[j0][k];
        float4 B1 = *(const float4*)&ebs[j0+1][k];
        float4 W  = *(const float4*)&w2s[k];
        acc00 = fmaf(W.x, frcp(fmaf(A0.x,B0.x,1.f)), acc00);
        acc01 = fmaf(W.x, frcp(fmaf(A0.x,B1.x,1.f)), acc01);
        acc10 = fmaf(W.x, frcp(fmaf(A1.x,B0.x,1.f)), acc10);
        acc11 = fmaf(W.x, frcp(fmaf(A1.x,B1.x,1.f)), acc11);
        acc00 = fmaf(W.y, frcp(fmaf(A0.y,B0.y,1.f)), acc00);
        acc01 = fmaf(W.y, frcp(fmaf(A0.y,B1.y,1.f)), acc01);
        acc10 = fmaf(W.y, frcp(fmaf(A1.y,B0.y,1.f)), acc10);
        acc11 = fmaf(W.y, frcp(fmaf(A1.y,B1.y,1.f)), acc11);
        acc00 = fmaf(W.z, frcp(fmaf(A0.z,B0.z,1.f)), acc00);
        acc01 = fmaf(W.z, frcp(fmaf(A0.z,B1.z,1.f)), acc01);
        acc10 = fmaf(W.z, frcp(fmaf(A1.z,B0.z,1.f)), acc10);
        acc11 = fmaf(W.z, frcp(fmaf(A1.z,B1.z,1.f)), acc11);
        acc00 = fmaf(W.w, frcp(fmaf(A0.w,B0.w,1.f)), acc00);
        acc01 = fmaf(W.w, frcp(fmaf(A0.w,B1.w,1.f)), acc01);
        acc10 = fmaf(W.w, frcp(fmaf(A1.w,B0.w,1.f)), acc10);
        acc11 = fmaf(W.w, frcp(fmaf(A1.w,B1.w,1.f)), acc11);
    }
    const int gi0 = it + i0, gj0 = jt + j0;
    out[((size_t)(gi0  )*128 + gj0  )*16 + b] = acc00;
    out[((size_t)(gi0  )*128 + gj0+1)*16 + b] = acc01;
    out[((size_t)(gi0+1)*128 + gj0  )*16 + b] = acc10;
    out[((size_t)(gi0+1)*128 + gj0+1)*16 + b] = acc11;
}

extern "C" void kernel_launch(void* const* d_in, const int* in_sizes, int n_in,
                              void* d_out, int out_size, void* d_ws, size_t ws_size,
                              hipStream_t stream)
{
    (void)in_sizes; (void)n_in; (void)out_size; (void)ws_size;
    const int*   widx = (const int*)d_in[0];
    const int*   pidx = (const int*)d_in[1];
    const float* wemb = (const float*)d_in[4];
    const float* temb = (const float*)d_in[5];
    const float* w_ih_l0f = (const float*)d_in[6];
    const float* w_hh_l0f = (const float*)d_in[7];
    const float* b_ih_l0f = (const float*)d_in[8];
    const float* b_hh_l0f = (const float*)d_in[9];
    const float* w_ih_l0b = (const float*)d_in[10];
    const float* w_hh_l0b = (const float*)d_in[11];
    const float* b_ih_l0b = (const float*)d_in[12];
    const float* b_hh_l0b = (const float*)d_in[13];
    const float* w_ih_l1f = (const float*)d_in[14];
    const float* w_hh_l1f = (const float*)d_in[15];
    const float* b_ih_l1f = (const float*)d_in[16];
    const float* b_hh_l1f = (const float*)d_in[17];
    const float* w_ih_l1b = (const float*)d_in[18];
    const float* w_hh_l1b = (const float*)d_in[19];
    const float* b_ih_l1b = (const float*)d_in[20];
    const float* b_hh_l1b = (const float*)d_in[21];
    const float* fc1_w = (const float*)d_in[22];
    const float* fc1_b = (const float*)d_in[23];
    const float* fc2_w = (const float*)d_in[24];
    const float* fc2_b = (const float*)d_in[25];

    float* ws  = (float*)d_ws;
    float* x   = ws;                  // 262144
    float* xp0 = x + 262144;          // 2 * 1048576
    float* h1  = xp0 + 2097152;       // 524288
    float* xp1 = h1 + 524288;         // 2 * 1048576
    float* h2  = xp1 + 2097152;       // 524288
    float* ea  = h2 + 524288;         // 204800
    float* eb  = ea + 204800;         // 204800
    unsigned* wpk0 = (unsigned*)(eb + 204800);   // 65536 uints (layer0 f16 weights)
    unsigned* wpk1 = wpk0 + 65536;               // 65536 uints (layer1)
    // total ~6.1M floats ~= 24.5 MB

    embed_kernel<<<1024, 256, 0, stream>>>(widx, pidx, wemb, temb, x);
    pack_kernel<<<256, 256, 0, stream>>>(w_hh_l0f, w_hh_l0b, wpk0);
    pack_kernel<<<256, 256, 0, stream>>>(w_hh_l1f, w_hh_l1b, wpk1);
    // layer 0 input projections (both dirs in grid.z), gate-permuted columns
    gemm_kernel<<<dim3(16,8,2), 256, 0, stream>>>(x, 128,
        w_ih_l0f, w_ih_l0b, 128,
        b_ih_l0f, b_hh_l0f, b_ih_l0b, b_hh_l0b,
        xp0, xp0 + 1048576, 512, 512, 0, 1);
    lstm_kernel<<<32, 512, 0, stream>>>(xp0, wpk0, h1);
    // layer 1 input projections, gate-permuted columns
    gemm_kernel<<<dim3(16,8,2), 256, 0, stream>>>(h1, 256,
        w_ih_l1f, w_ih_l1b, 256,
        b_ih_l1f, b_hh_l1f, b_ih_l1b, b_hh_l1b,
        xp1, xp1 + 1048576, 512, 512, 0, 1);
    lstm_kernel<<<32, 512, 0, stream>>>(xp1, wpk1, h2);
    // fc1: a = h2@wa^T -> ea = exp(2a); bp = h2@wb^T + fc1_b -> eb = exp(2bp)
    gemm_kernel<<<dim3(16,2,2), 256, 0, stream>>>(h2, 256,
        fc1_w, fc1_w + 256, 512,
        nullptr, nullptr, fc1_b, nullptr,
        ea, eb, 100, 100, 1, 0);
    pair_kernel<<<dim3(4,4,16), 256, 0, stream>>>(ea, eb, fc2_w, fc2_b, (float*)d_out);
}